// Round 6
// baseline (113.409 us; speedup 1.0000x reference)
//
#include <hip/hip_runtime.h>
#include <hip/hip_bf16.h>

#define INV_SQRT2      0.7071067811865476f
#define INV_SQRT_2PI   0.3989422804014327f

typedef float f32x4 __attribute__((ext_vector_type(4)));

__device__ __forceinline__ float grad_gelu(float x) {
    float cdf = 0.5f * (1.0f + erff(x * INV_SQRT2));
    float pdf = INV_SQRT_2PI * __expf(-0.5f * x * x);
    return cdf + x * pdf;
}

__device__ __forceinline__ f32x4 grad_gelu4(f32x4 v) {
    f32x4 r;
    r.x = grad_gelu(v.x);
    r.y = grad_gelu(v.y);
    r.z = grad_gelu(v.z);
    r.w = grad_gelu(v.w);
    return r;
}

// Persistent grid-stride: 2048 blocks (~8/CU), contiguous wave-coalesced
// accesses, normal cached loads/stores (nt-stores measured -17% in R3).
__global__ __launch_bounds__(256) void grad_gelu_kernel(const f32x4* __restrict__ in,
                                                        f32x4* __restrict__ out,
                                                        int n4) {
    const int stride = gridDim.x * blockDim.x;
    for (int i = blockIdx.x * blockDim.x + threadIdx.x; i < n4; i += stride) {
        out[i] = grad_gelu4(in[i]);
    }
}

extern "C" void kernel_launch(void* const* d_in, const int* in_sizes, int n_in,
                              void* d_out, int out_size, void* d_ws, size_t ws_size,
                              hipStream_t stream) {
    const float* x = (const float*)d_in[0];
    float* out = (float*)d_out;
    int n = in_sizes[0];           // 16*2048*2048 = 67108864, divisible by 4
    int n4 = n >> 2;               // 16777216 float4s
    int block = 256;
    int grid = 2048;               // 8 blocks/CU resident, persistent waves
    grad_gelu_kernel<<<grid, block, 0, stream>>>((const f32x4*)x, (f32x4*)out, n4);
}

// Round 7
// 91.153 us; speedup vs baseline: 1.2442x; 1.2442x over previous
//
#include <hip/hip_runtime.h>
#include <hip/hip_bf16.h>

#define INV_SQRT2      0.7071067811865476f
#define INV_SQRT_2PI   0.3989422804014327f

typedef float f32x4 __attribute__((ext_vector_type(4)));

__device__ __forceinline__ float grad_gelu(float x) {
    float cdf = 0.5f * (1.0f + erff(x * INV_SQRT2));
    float pdf = INV_SQRT_2PI * __expf(-0.5f * x * x);
    return cdf + x * pdf;
}

// One float4 per thread, one-shot exact grid. Empirically the fastest
// structure (R1: 91.6us = 93% of the 6.29 TB/s copy ceiling). All
// alternatives regressed: per-thread ILP unroll (98.3), grid-stride
// (113.4), grid-stride+nt (107.5), tanh math (93.7).
// n = 67108864 = 65536 blocks * 256 threads * 4 floats: no bounds check.
__global__ __launch_bounds__(256) void grad_gelu_kernel(const f32x4* __restrict__ in,
                                                        f32x4* __restrict__ out) {
    int i = blockIdx.x * blockDim.x + threadIdx.x;
    f32x4 v = in[i];
    f32x4 r;
    r.x = grad_gelu(v.x);
    r.y = grad_gelu(v.y);
    r.z = grad_gelu(v.z);
    r.w = grad_gelu(v.w);
    out[i] = r;
}

extern "C" void kernel_launch(void* const* d_in, const int* in_sizes, int n_in,
                              void* d_out, int out_size, void* d_ws, size_t ws_size,
                              hipStream_t stream) {
    const float* x = (const float*)d_in[0];
    float* out = (float*)d_out;
    int n = in_sizes[0];           // 16*2048*2048 = 67108864
    int n4 = n >> 2;               // 16777216 float4s
    int grid = n4 / 256;           // 65536 blocks, exact cover
    grad_gelu_kernel<<<grid, 256, 0, stream>>>((const f32x4*)x, (f32x4*)out);
}